// Round 1
// baseline (3153.210 us; speedup 1.0000x reference)
//
#include <hip/hip_runtime.h>
#include <math.h>

// Problem constants (from reference): B=131072, T=16, D=2, H=64
#define BSZ 131072
#define TT  16
#define DD  2
#define HH  64
#define BLK 128   // threads/block; 128*65*4B = 33.3 KB LDS -> 4 blocks/CU

__device__ __forceinline__ float fast_sigmoid(float v) {
    return 1.0f / (1.0f + __expf(-v));
}
__device__ __forceinline__ float fast_tanh(float v) {
    // tanh(v) = 1 - 2/(1+e^{2v}); stable for the bounded pre-activations here
    return 1.0f - 2.0f / (1.0f + __expf(2.0f * v));
}

__global__ __launch_bounds__(BLK, 2) void flow_kernel(
    const float* __restrict__ x,     // (B,T,D)
    const float* __restrict__ z,     // (B,H)
    const float* __restrict__ W_ih,  // (3H,D)
    const float* __restrict__ W_hh,  // (3H,H)
    const float* __restrict__ b_ih,  // (3H)
    const float* __restrict__ b_hh,  // (3H)
    const float* __restrict__ W1,    // (H,32)
    const float* __restrict__ b1,    // (32)
    const float* __restrict__ W2,    // (32,4)
    const float* __restrict__ b2,    // (4)
    float* __restrict__ y_out,       // (B,T,D)
    float* __restrict__ lad_out)     // (B)
{
    // new-h staging: per-thread 64 floats, stride 65 to break bank aliasing
    __shared__ float lds_hn[BLK * 65];
    const int tid = threadIdx.x;
    const int b   = blockIdx.x * BLK + tid;
    float* hn = &lds_hn[tid * 65];

    // h lives in registers (k fully unrolled everywhere)
    float h[HH];
    #pragma unroll
    for (int k = 0; k < HH; ++k) h[k] = z[(size_t)b * HH + k];

    const float2* xp = (const float2*)(x + (size_t)b * (TT * DD));
    float2*       yp = (float2*)(y_out + (size_t)b * (TT * DD));

    float y0 = 0.0f, y1 = 0.0f, lad = 0.0f;

    #pragma unroll 1
    for (int t = 0; t < TT; ++t) {
        const float2 xt = xp[t];

        // ---- GRU: j loop rolled (uniform j -> scalar weight loads) ----
        #pragma unroll 1
        for (int j = 0; j < HH; ++j) {
            float ar = 0.0f, az = 0.0f, an = 0.0f;
            const float* wr = W_hh + j * HH;
            const float* wz = W_hh + (HH + j) * HH;
            const float* wn = W_hh + (2 * HH + j) * HH;
            #pragma unroll
            for (int k = 0; k < HH; ++k) {
                ar = fmaf(wr[k], h[k], ar);
                az = fmaf(wz[k], h[k], az);
                an = fmaf(wn[k], h[k], an);
            }
            const float gir = fmaf(W_ih[2*j+1],          y1,
                              fmaf(W_ih[2*j],            y0, b_ih[j]));
            const float giz = fmaf(W_ih[2*(HH+j)+1],     y1,
                              fmaf(W_ih[2*(HH+j)],       y0, b_ih[HH+j]));
            const float gin = fmaf(W_ih[2*(2*HH+j)+1],   y1,
                              fmaf(W_ih[2*(2*HH+j)],     y0, b_ih[2*HH+j]));
            const float r = fast_sigmoid(gir + ar + b_hh[j]);
            const float u = fast_sigmoid(giz + az + b_hh[HH + j]);
            const float n = fast_tanh(fmaf(r, an + b_hh[2*HH + j], gin));
            hn[j] = (1.0f - u) * n + u * h[j];   // defer h update: old h needed by all j
        }
        #pragma unroll
        for (int k = 0; k < HH; ++k) h[k] = hn[k];

        // ---- MLP: hid = relu(h @ W1 + b1) ----
        float hid[32];
        #pragma unroll
        for (int i = 0; i < 32; ++i) hid[i] = b1[i];
        #pragma unroll 1
        for (int k = 0; k < HH; ++k) {          // k rolled: hk from LDS, W1 row scalar-loaded
            const float hk = hn[k];
            #pragma unroll
            for (int i = 0; i < 32; ++i)
                hid[i] = fmaf(hk, W1[k * 32 + i], hid[i]);
        }
        #pragma unroll
        for (int i = 0; i < 32; ++i) hid[i] = fmaxf(hid[i], 0.0f);

        // ---- ls = hid @ W2 + b2 ----
        float ls0 = b2[0], ls1 = b2[1], ls2 = b2[2], ls3 = b2[3];
        #pragma unroll
        for (int i = 0; i < 32; ++i) {
            ls0 = fmaf(hid[i], W2[i * 4 + 0], ls0);
            ls1 = fmaf(hid[i], W2[i * 4 + 1], ls1);
            ls2 = fmaf(hid[i], W2[i * 4 + 2], ls2);
            ls3 = fmaf(hid[i], W2[i * 4 + 3], ls3);
        }

        // ---- y update: softplus scale, affine flow step ----
        const float s0 = log1pf(__expf(ls2)) + 0.001f;
        const float s1 = log1pf(__expf(ls3)) + 0.001f;
        y0 = y0 + ls0 + s0 * xt.x;
        y1 = y1 + ls1 + s1 * xt.y;
        lad += __logf(s0) + __logf(s1);
        yp[t] = make_float2(y0, y1);
    }
    lad_out[b] = lad;
}

extern "C" void kernel_launch(void* const* d_in, const int* in_sizes, int n_in,
                              void* d_out, int out_size, void* d_ws, size_t ws_size,
                              hipStream_t stream) {
    const float* x    = (const float*)d_in[0];
    const float* z    = (const float*)d_in[1];
    const float* W_ih = (const float*)d_in[2];
    const float* W_hh = (const float*)d_in[3];
    const float* b_ih = (const float*)d_in[4];
    const float* b_hh = (const float*)d_in[5];
    const float* W1   = (const float*)d_in[6];
    const float* b1   = (const float*)d_in[7];
    const float* W2   = (const float*)d_in[8];
    const float* b2   = (const float*)d_in[9];

    float* y_out   = (float*)d_out;                       // (B,T,D) flat
    float* lad_out = y_out + (size_t)BSZ * TT * DD;       // (B,)

    dim3 grid(BSZ / BLK), block(BLK);
    hipLaunchKernelGGL(flow_kernel, grid, block, 0, stream,
                       x, z, W_ih, W_hh, b_ih, b_hh, W1, b1, W2, b2,
                       y_out, lad_out);
}

// Round 2
// 289.518 us; speedup vs baseline: 10.8912x; 10.8912x over previous
//
#include <hip/hip_runtime.h>

// B=131072, T=16, D=2, H=64. 16 batch rows per wave, 4 waves (64 rows) per block.
#define BSZ 131072
#define TT  16
#define RPB 64     // rows per block
#define BLK 256

typedef __bf16 bf16x8 __attribute__((ext_vector_type(8)));
typedef float  f32x4  __attribute__((ext_vector_type(4)));

#define MFMA(a, b, c) __builtin_amdgcn_mfma_f32_16x16x32_bf16((a), (b), (c), 0, 0, 0)

__device__ __forceinline__ float rcp_fast(float xx) {
    float r; asm("v_rcp_f32 %0, %1" : "=v"(r) : "v"(xx)); return r;
}
__device__ __forceinline__ float sigmoid_f(float v) { return rcp_fast(1.0f + __expf(-v)); }
__device__ __forceinline__ float tanh_f(float v)    { return 1.0f - 2.0f * rcp_fast(1.0f + __expf(2.0f * v)); }

__global__ __launch_bounds__(BLK, 2) void flow_mfma(
    const float* __restrict__ x,     // (B,16,2)
    const float* __restrict__ z,     // (B,64)
    const float* __restrict__ W_ih,  // (192,2)
    const float* __restrict__ W_hh,  // (192,64)
    const float* __restrict__ b_ih,  // (192)
    const float* __restrict__ b_hh,  // (192)
    const float* __restrict__ W1,    // (64,32)
    const float* __restrict__ b1,    // (32)
    const float* __restrict__ W2,    // (32,4)
    const float* __restrict__ b2,    // (4)
    float* __restrict__ y_out,       // (B,16,2)
    float* __restrict__ lad_out)     // (B)
{
    // hbuf: bf16 h state, row-major, stride 72 (144B: row->row bank offset 4, 16B-aligned)
    __shared__ __align__(16) __bf16 hbuf[RPB * 72];     // 9.2 KB
    __shared__ __align__(16) __bf16 hidbuf[RPB * 40];   // 5 KB
    __shared__ __align__(16) float4 gi_tab[192];        // {W_ih[j][0], W_ih[j][1], bias, b_hh} 3 KB
    __shared__ __align__(16) float  lsbuf[RPB * 4];     // 1 KB
    __shared__ __align__(16) float2 ystate[RPB];        // 0.5 KB
    __shared__ __align__(16) float2 ybuf[RPB * TT];     // 8 KB

    const int tid  = threadIdx.x;
    const int lane = tid & 63, wave = tid >> 6;
    const int quad = lane >> 4, n16 = lane & 15;
    const int gb   = blockIdx.x * RPB;
    const f32x4 zero = {0.f, 0.f, 0.f, 0.f};

    // ---- stage gi table: per column j: {Wih0, Wih1, b_ih(+b_hh for r,z), b_hh(n only)} ----
    if (tid < 192) {
        const int j = tid;
        const float w0 = W_ih[2*j], w1 = W_ih[2*j+1];
        const float bi = b_ih[j], bh = b_hh[j];
        gi_tab[j] = (j < 128) ? make_float4(w0, w1, bi + bh, 0.f)
                              : make_float4(w0, w1, bi, bh);
    }
    if (tid < RPB) ystate[tid] = make_float2(0.f, 0.f);

    // ---- stage z -> hbuf (bf16, coalesced) ----
    #pragma unroll
    for (int r4 = 0; r4 < 4; ++r4) {
        const int row = (tid >> 4) + r4 * 16;
        const int col = (tid & 15) * 4;
        const float4 zv = *(const float4*)&z[(size_t)(gb + row) * 64 + col];
        hbuf[row*72 + col + 0] = (__bf16)zv.x;
        hbuf[row*72 + col + 1] = (__bf16)zv.y;
        hbuf[row*72 + col + 2] = (__bf16)zv.z;
        hbuf[row*72 + col + 3] = (__bf16)zv.w;
    }

    // ---- weight B-fragments in registers (bf16): B[k][n], n=lane&15, k=quad*8+j ----
    bf16x8 Whh[12][2];             // (64 x 192), from W_hh^T: row ct*16+n of W_hh, contiguous k
    #pragma unroll
    for (int ct = 0; ct < 12; ++ct)
        #pragma unroll
        for (int kt = 0; kt < 2; ++kt) {
            const float* p = W_hh + (size_t)(ct*16 + n16) * 64 + kt*32 + quad*8;
            bf16x8 f;
            #pragma unroll
            for (int j = 0; j < 8; ++j) f[j] = (__bf16)p[j];
            Whh[ct][kt] = f;
        }
    bf16x8 W1f[2][2];              // (64 x 32) column reads, stride 32
    #pragma unroll
    for (int c2 = 0; c2 < 2; ++c2)
        #pragma unroll
        for (int kt = 0; kt < 2; ++kt) {
            bf16x8 f;
            #pragma unroll
            for (int j = 0; j < 8; ++j)
                f[j] = (__bf16)W1[(size_t)(kt*32 + quad*8 + j) * 32 + c2*16 + n16];
            W1f[c2][kt] = f;
        }
    bf16x8 W2f;                    // (32 x 4) padded to 16 cols
    #pragma unroll
    for (int j = 0; j < 8; ++j)
        W2f[j] = (n16 < 4) ? (__bf16)W2[(size_t)(quad*8 + j) * 4 + n16] : (__bf16)0.f;

    const float b1v0 = b1[n16], b1v1 = b1[16 + n16];
    const float4 b2v = *(const float4*)b2;

    // ---- h state in C-layout fp32 regs: hst[ct][i] = h[row=quad*4+i][col=ct*16+n16] ----
    f32x4 hst[4];
    #pragma unroll
    for (int ct = 0; ct < 4; ++ct)
        #pragma unroll
        for (int i = 0; i < 4; ++i)
            hst[ct][i] = z[(size_t)(gb + wave*16 + quad*4 + i) * 64 + ct*16 + n16];

    __syncthreads();   // only barrier: after this, waves are fully independent

    float y0 = 0.f, y1 = 0.f, lad = 0.f;
    const float* xrow = x + (size_t)(gb + wave*16 + lane) * (TT*2);   // valid for lane<16
    const int arow = wave*16 + n16;

    #pragma unroll 1
    for (int t = 0; t < TT; ++t) {
        // A-frags of current h (bf16): A[m=n16][k=quad*8+j]
        bf16x8 a0 = *(const bf16x8*)&hbuf[arow*72 + quad*8];
        bf16x8 a1 = *(const bf16x8*)&hbuf[arow*72 + 32 + quad*8];

        // y_{t-1} for this lane's 4 C-rows
        float ys0[4], ys1[4];
        #pragma unroll
        for (int i = 0; i < 4; ++i) {
            const float2 yv = ystate[wave*16 + quad*4 + i];
            ys0[i] = yv.x; ys1[i] = yv.y;
        }

        // ---- GRU: per col-group g, 6 MFMA then elementwise gates (keeps C live at 12 regs) ----
        #pragma unroll
        for (int g = 0; g < 4; ++g) {
            f32x4 cr = MFMA(a0, Whh[g  ][0], zero); cr = MFMA(a1, Whh[g  ][1], cr);
            f32x4 cz = MFMA(a0, Whh[g+4][0], zero); cz = MFMA(a1, Whh[g+4][1], cz);
            f32x4 cn = MFMA(a0, Whh[g+8][0], zero); cn = MFMA(a1, Whh[g+8][1], cn);
            const float4 Tr = gi_tab[      g*16 + n16];
            const float4 Tz = gi_tab[ 64 + g*16 + n16];
            const float4 Tn = gi_tab[128 + g*16 + n16];
            #pragma unroll
            for (int i = 0; i < 4; ++i) {
                const float gir = fmaf(Tr.x, ys0[i], fmaf(Tr.y, ys1[i], Tr.z));
                const float giz = fmaf(Tz.x, ys0[i], fmaf(Tz.y, ys1[i], Tz.z));
                const float gin = fmaf(Tn.x, ys0[i], fmaf(Tn.y, ys1[i], Tn.z));
                const float r  = sigmoid_f(gir + cr[i]);
                const float u  = sigmoid_f(giz + cz[i]);
                const float nn = tanh_f(fmaf(r, cn[i] + Tn.w, gin));
                const float hv = fmaf(u, hst[g][i] - nn, nn);   // (1-u)*n + u*h
                hst[g][i] = hv;
                hbuf[(wave*16 + quad*4 + i)*72 + g*16 + n16] = (__bf16)hv;
            }
        }

        // ---- MLP1: hid = relu(h_new @ W1 + b1) ----
        bf16x8 h0 = *(const bf16x8*)&hbuf[arow*72 + quad*8];
        bf16x8 h1 = *(const bf16x8*)&hbuf[arow*72 + 32 + quad*8];
        #pragma unroll
        for (int c2 = 0; c2 < 2; ++c2) {
            f32x4 hc = MFMA(h0, W1f[c2][0], zero); hc = MFMA(h1, W1f[c2][1], hc);
            const float bb = c2 ? b1v1 : b1v0;
            #pragma unroll
            for (int i = 0; i < 4; ++i) {
                const float v = fmaxf(hc[i] + bb, 0.f);
                hidbuf[(wave*16 + quad*4 + i)*40 + c2*16 + n16] = (__bf16)v;
            }
        }

        // ---- MLP2: ls = hid @ W2 (+b2 later), K=32 one MFMA ----
        bf16x8 ha = *(const bf16x8*)&hidbuf[arow*40 + quad*8];
        f32x4 ls = MFMA(ha, W2f, zero);
        if (n16 < 4) {
            #pragma unroll
            for (int i = 0; i < 4; ++i)
                lsbuf[(wave*16 + quad*4 + i)*4 + n16] = ls[i];
        }

        // ---- per-row epilogue: lanes 0..15 own rows 0..15 of the wave strip ----
        if (lane < 16) {
            const int rl = wave*16 + lane;
            const float4 L = *(const float4*)&lsbuf[rl*4];
            const float l0 = L.x + b2v.x, l1 = L.y + b2v.y;
            const float l2 = L.z + b2v.z, l3 = L.w + b2v.w;
            const float s0 = __logf(1.0f + __expf(l2)) + 0.001f;
            const float s1 = __logf(1.0f + __expf(l3)) + 0.001f;
            const float2 xt = *(const float2*)&xrow[t*2];
            y0 += l0 + s0 * xt.x;
            y1 += l1 + s1 * xt.y;
            lad += __logf(s0) + __logf(s1);
            ystate[rl] = make_float2(y0, y1);
            ybuf[rl*TT + t] = make_float2(y0, y1);
        }
    }

    // ---- coalesced y write: ybuf strip layout == global layout for this wave's rows ----
    const float4* yb4 = (const float4*)ybuf;
    float4* yg4 = (float4*)(y_out + (size_t)gb * (TT*2));
    #pragma unroll
    for (int it = 0; it < 2; ++it) {
        const int idx = wave*128 + it*64 + lane;   // 128 float4 per wave strip
        yg4[idx] = yb4[idx];
    }
    if (lane < 16) lad_out[gb + wave*16 + lane] = lad;
}

extern "C" void kernel_launch(void* const* d_in, const int* in_sizes, int n_in,
                              void* d_out, int out_size, void* d_ws, size_t ws_size,
                              hipStream_t stream) {
    const float* x    = (const float*)d_in[0];
    const float* z    = (const float*)d_in[1];
    const float* W_ih = (const float*)d_in[2];
    const float* W_hh = (const float*)d_in[3];
    const float* b_ih = (const float*)d_in[4];
    const float* b_hh = (const float*)d_in[5];
    const float* W1   = (const float*)d_in[6];
    const float* b1   = (const float*)d_in[7];
    const float* W2   = (const float*)d_in[8];
    const float* b2   = (const float*)d_in[9];

    float* y_out   = (float*)d_out;
    float* lad_out = y_out + (size_t)BSZ * TT * 2;

    dim3 grid(BSZ / RPB), block(BLK);
    hipLaunchKernelGGL(flow_mfma, grid, block, 0, stream,
                       x, z, W_ih, W_hh, b_ih, b_hh, W1, b1, W2, b2,
                       y_out, lad_out);
}